// Round 5
// baseline (344.858 us; speedup 1.0000x reference)
//
#include <hip/hip_runtime.h>
#include <hip/hip_bf16.h>
#include <hip/hip_cooperative_groups.h>

namespace cg = cooperative_groups;

// Problem dims (fixed by setup_inputs)
constexpr int B = 4, H = 8, N = 4096, E = 64, D = 512;   // d_model = H*E = 512
constexpr int BH = B * H;          // 32
constexpr int CHUNK = 32;          // positions per chunk
constexpr int NCH = N / CHUNK;     // 128 chunks per (b,h); 4096 chunks total
constexpr float EPS = 1e-5f;
constexpr int TM = 128, TN = 128, BK = 64;   // GEMM tiling: 128x4 = 512 tiles

typedef __attribute__((ext_vector_type(4))) float floatx4;
typedef __attribute__((ext_vector_type(8))) short short8;

__device__ __forceinline__ float phi(float x) {
    return (x > 0.0f) ? (x + 1.0f) : __expf(x);   // elu(x) + 1
}

// ---------------------------------------------------------------------------
// Fused cooperative kernel: 512 blocks x 256 threads (2 blocks/CU needed —
// robust: launch_bounds(256,2) gives a 256-reg combined VGPR+AGPR budget).
// Each wave owns 2 chunks of 32 positions.
// Phase A : local cumsums of phi(k), v in REGISTERS; chunk totals to
//           ksumT[bh*64+e][ch] (transposed); W -> bf16.
// Phase B1: exclusive prefix over 128 chunks per (bh,e) — all 2048 waves.
// Phase B2: read q, s = wave-sum phi(q)*kc, attn = s/(s+eps)*vc -> bf16
//           in [b, n, h*e] layout.
// Phase C : out = attn @ wb^T + bias (R3's proven 128x128 MFMA tile,
//           global_load_lds width-16 staging, XOR-swizzled LDS columns).
// ---------------------------------------------------------------------------
__global__ __launch_bounds__(256, 2) void fused_linattn(
        const float* __restrict__ q, const float* __restrict__ k,
        const float* __restrict__ v, const float* __restrict__ W,
        const float* __restrict__ bias,
        __hip_bfloat16* __restrict__ wb,
        float* __restrict__ ksumT, float* __restrict__ vsumT,
        __hip_bfloat16* __restrict__ attn,
        float* __restrict__ out) {
    __shared__ short Alds[TM * BK];   // 16 KiB
    __shared__ short Blds[TN * BK];   // 16 KiB
    cg::grid_group grid = cg::this_grid();

    const int tid = threadIdx.x;
    const int w = tid >> 6;                   // wave in block 0..3
    const int lane = tid & 63;                // = e in phases A/B
    const int wave = (blockIdx.x << 2) | w;   // 0..2047
    const int c0 = wave << 1;                 // first of 2 global chunk ids
    const int bh = c0 >> 7;

    // ---------------- Phase A ----------------
    // W -> bf16 (512*256 threads x 2 = 512*512 elements)
    {
        int gid = blockIdx.x * 256 + tid;
        wb[gid] = __float2bfloat16(W[gid]);
        wb[gid + 131072] = __float2bfloat16(W[gid + 131072]);
    }

    float kcl[2][CHUNK], vcl[2][CHUNK];   // per-position local inclusive cumsums
    #pragma unroll
    for (int c = 0; c < 2; c++) {
        size_t bb = (size_t)(c0 + c) * CHUNK * E + lane;
        const float* kp = k + bb;
        const float* vp = v + bb;
        float kc = 0.f, vc = 0.f;
        #pragma unroll
        for (int g = 0; g < 4; g++) {
            float kb[8], vb[8];
            #pragma unroll
            for (int j = 0; j < 8; j++) {
                size_t o = (size_t)(g * 8 + j) * E;
                kb[j] = kp[o]; vb[j] = vp[o];
            }
            #pragma unroll
            for (int j = 0; j < 8; j++) {
                kc += phi(kb[j]);
                vc += vb[j];
                kcl[c][g * 8 + j] = kc;
                vcl[c][g * 8 + j] = vc;
            }
        }
        int ch = (c0 + c) & 127;
        ksumT[(size_t)(bh * E + lane) * NCH + ch] = kc;
        vsumT[(size_t)(bh * E + lane) * NCH + ch] = vc;
    }

    grid.sync();

    // ---------------- Phase B1: exclusive prefix over chunks ----------------
    {
        size_t pb = (size_t)wave * NCH;   // row = bh*64 + e, 0..2047 (all waves)
        float x0 = ksumT[pb + lane],      y0 = vsumT[pb + lane];
        float x1 = ksumT[pb + 64 + lane], y1 = vsumT[pb + 64 + lane];
        float ox0 = x0, oy0 = y0, ox1 = x1, oy1 = y1;
        #pragma unroll
        for (int dlt = 1; dlt < 64; dlt <<= 1) {
            float t0 = __shfl_up(x0, dlt, 64);
            float u0 = __shfl_up(y0, dlt, 64);
            float t1 = __shfl_up(x1, dlt, 64);
            float u1 = __shfl_up(y1, dlt, 64);
            if (lane >= dlt) { x0 += t0; y0 += u0; x1 += t1; y1 += u1; }
        }
        float tx = __shfl(x0, 63, 64);
        float ty = __shfl(y0, 63, 64);
        ksumT[pb + lane]      = x0 - ox0;
        vsumT[pb + lane]      = y0 - oy0;
        ksumT[pb + 64 + lane] = x1 - ox1 + tx;
        vsumT[pb + 64 + lane] = y1 - oy1 + ty;
    }

    grid.sync();

    // ---------------- Phase B2: scan + attn store ----------------
    {
        int b_ = bh >> 3, h_ = bh & 7;
        #pragma unroll
        for (int c = 0; c < 2; c++) {
            int ch = (c0 + c) & 127;
            float koff = ksumT[(size_t)(bh * E + lane) * NCH + ch];
            float voff = vsumT[(size_t)(bh * E + lane) * NCH + ch];
            const float* qp = q + (size_t)(c0 + c) * CHUNK * E + lane;
            __hip_bfloat16* op = attn + ((size_t)(b_ * N + ch * CHUNK)) * D + h_ * E + lane;
            #pragma unroll
            for (int g = 0; g < 4; g++) {
                float qb[8], pr[8];
                #pragma unroll
                for (int j = 0; j < 8; j++) qb[j] = qp[(size_t)(g * 8 + j) * E];
                #pragma unroll
                for (int j = 0; j < 8; j++) pr[j] = phi(qb[j]) * (koff + kcl[c][g * 8 + j]);
                #pragma unroll
                for (int m = 1; m < 64; m <<= 1) {
                    #pragma unroll
                    for (int j = 0; j < 8; j++) pr[j] += __shfl_xor(pr[j], m, 64);
                }
                #pragma unroll
                for (int j = 0; j < 8; j++) {
                    float s = pr[j];
                    op[(size_t)(g * 8 + j) * D] =
                        __float2bfloat16(s / (s + EPS) * (voff + vcl[c][g * 8 + j]));
                }
            }
        }
    }

    grid.sync();

    // ---------------- Phase C: GEMM out = attn @ wb^T + bias ----------------
    {
        const int tile = blockIdx.x;                 // 128 M-tiles x 4 N-tiles
        const int tm = tile >> 2, tn = tile & 3;
        const int lo = lane & 15, quad = lane >> 4;
        const int wm = w & 1, wn = w >> 1;
        const int srow = lane >> 3;                  // 0..7
        const int cgp = lane & 7;                    // colgrp slot

        floatx4 acc[4][4] = {};
        const short* Ag = (const short*)attn;
        const short* Bg = (const short*)wb;

        for (int k0 = 0; k0 < D; k0 += BK) {
            __syncthreads();
            #pragma unroll
            for (int t = 0; t < 4; t++) {
                int r = w * 32 + t * 8 + srow;
                int gg = cgp ^ srow;
                const short* ga = Ag + (size_t)(tm * TM + r) * D + k0 + gg * 8;
                const short* gb = Bg + (size_t)(tn * TN + r) * D + k0 + gg * 8;
                __builtin_amdgcn_global_load_lds(
                    (const __attribute__((address_space(1))) void*)ga,
                    (__attribute__((address_space(3))) void*)&Alds[(w * 32 + t * 8) * BK],
                    16, 0, 0);
                __builtin_amdgcn_global_load_lds(
                    (const __attribute__((address_space(1))) void*)gb,
                    (__attribute__((address_space(3))) void*)&Blds[(w * 32 + t * 8) * BK],
                    16, 0, 0);
            }
            __syncthreads();
            #pragma unroll
            for (int kk = 0; kk < 2; kk++) {
                short8 af[4], bfr[4];
                #pragma unroll
                for (int i = 0; i < 4; i++) {
                    int ra = wm * 64 + i * 16 + lo;
                    af[i] = *(const short8*)&Alds[ra * BK + (((kk << 2) | quad) ^ (lo & 7)) * 8];
                    int rb = wn * 64 + i * 16 + lo;
                    bfr[i] = *(const short8*)&Blds[rb * BK + (((kk << 2) | quad) ^ (lo & 7)) * 8];
                }
                #pragma unroll
                for (int i = 0; i < 4; i++)
                    #pragma unroll
                    for (int j = 0; j < 4; j++)
                        acc[i][j] = __builtin_amdgcn_mfma_f32_16x16x32_bf16(af[i], bfr[j], acc[i][j], 0, 0, 0);
            }
        }

        #pragma unroll
        for (int i = 0; i < 4; i++) {
            #pragma unroll
            for (int j = 0; j < 4; j++) {
                int n = tn * TN + wn * 64 + j * 16 + lo;
                float bv = bias[n];
                #pragma unroll
                for (int r = 0; r < 4; r++) {
                    int m = tm * TM + wm * 64 + i * 16 + quad * 4 + r;
                    out[(size_t)m * D + n] = acc[i][j][r] + bv;
                }
            }
        }
    }
}

// ===========================================================================
// Fallback path: R3's proven 5-kernel sequence (used only if the cooperative
// launch is rejected — e.g. graph-capture or occupancy surprise).
// ===========================================================================
__global__ void chunk_sums(const float* __restrict__ k, const float* __restrict__ v,
                           float* __restrict__ ksumT, float* __restrict__ vsumT) {
    int wave = (blockIdx.x << 2) | (threadIdx.x >> 6);
    int lane = threadIdx.x & 63;
    int bh = wave >> 7, ch = wave & 127;
    int qd = lane >> 4;
    int c  = lane & 15;
    const float* kp = k + ((size_t)bh * N + (size_t)ch * CHUNK) * E;
    const float* vp = v + ((size_t)bh * N + (size_t)ch * CHUNK) * E;
    floatx4 ks = {0.f, 0.f, 0.f, 0.f}, vs = {0.f, 0.f, 0.f, 0.f};
    #pragma unroll
    for (int i = 0; i < CHUNK / 4; i++) {
        int off = (i * 4 + qd) * E + c * 4;
        floatx4 kv = *(const floatx4*)(kp + off);
        floatx4 vv = *(const floatx4*)(vp + off);
        #pragma unroll
        for (int j = 0; j < 4; j++) ks[j] += phi(kv[j]);
        vs += vv;
    }
    #pragma unroll
    for (int j = 0; j < 4; j++) {
        ks[j] += __shfl_xor(ks[j], 16, 64);
        ks[j] += __shfl_xor(ks[j], 32, 64);
        vs[j] += __shfl_xor(vs[j], 16, 64);
        vs[j] += __shfl_xor(vs[j], 32, 64);
    }
    int d = c * 4 + qd;
    ksumT[(size_t)(bh * E + d) * NCH + ch] = ks[qd];
    vsumT[(size_t)(bh * E + d) * NCH + ch] = vs[qd];
}

__global__ void chunk_prefix(float* __restrict__ ksumT, float* __restrict__ vsumT) {
    int wid = (blockIdx.x << 2) | (threadIdx.x >> 6);
    int lane = threadIdx.x & 63;
    size_t base = (size_t)wid * NCH;
    float x0 = ksumT[base + lane],      y0 = vsumT[base + lane];
    float x1 = ksumT[base + 64 + lane], y1 = vsumT[base + 64 + lane];
    float ox0 = x0, oy0 = y0, ox1 = x1, oy1 = y1;
    #pragma unroll
    for (int dlt = 1; dlt < 64; dlt <<= 1) {
        float t0 = __shfl_up(x0, dlt, 64);
        float u0 = __shfl_up(y0, dlt, 64);
        float t1 = __shfl_up(x1, dlt, 64);
        float u1 = __shfl_up(y1, dlt, 64);
        if (lane >= dlt) { x0 += t0; y0 += u0; x1 += t1; y1 += u1; }
    }
    float tx = __shfl(x0, 63, 64);
    float ty = __shfl(y0, 63, 64);
    ksumT[base + lane]      = x0 - ox0;
    vsumT[base + lane]      = y0 - oy0;
    ksumT[base + 64 + lane] = x1 - ox1 + tx;
    vsumT[base + 64 + lane] = y1 - oy1 + ty;
}

__global__ void scan_attn(const float* __restrict__ q, const float* __restrict__ k,
                          const float* __restrict__ v,
                          const float* __restrict__ ksumT, const float* __restrict__ vsumT,
                          __hip_bfloat16* __restrict__ attn) {
    int wave = (blockIdx.x << 2) | (threadIdx.x >> 6);
    int lane = threadIdx.x & 63;
    int bh = wave >> 7, ch = wave & 127;
    int b = bh >> 3, h = bh & 7;
    size_t base = ((size_t)bh * N + (size_t)ch * CHUNK) * E + lane;
    const float* qp = q + base;
    const float* kp = k + base;
    const float* vp = v + base;
    float kc = ksumT[(size_t)(bh * E + lane) * NCH + ch];
    float vc = vsumT[(size_t)(bh * E + lane) * NCH + ch];
    __hip_bfloat16* op = attn + ((size_t)(b * N + ch * CHUNK)) * D + h * E + lane;

    #pragma unroll
    for (int g = 0; g < 2; g++) {
        float kA[16], qA[16], vA[16], pr[16], vs[16];
        #pragma unroll
        for (int j = 0; j < 16; j++) {
            size_t o = (size_t)(g * 16 + j) * E;
            kA[j] = kp[o]; qA[j] = qp[o]; vA[j] = vp[o];
        }
        #pragma unroll
        for (int j = 0; j < 16; j++) {
            kc += phi(kA[j]);
            vc += vA[j];
            pr[j] = phi(qA[j]) * kc;
            vs[j] = vc;
        }
        #pragma unroll
        for (int m = 1; m < 64; m <<= 1) {
            #pragma unroll
            for (int j = 0; j < 16; j++) pr[j] += __shfl_xor(pr[j], m, 64);
        }
        #pragma unroll
        for (int j = 0; j < 16; j++) {
            float s = pr[j];
            op[(size_t)(g * 16 + j) * D] = __float2bfloat16(s / (s + EPS) * vs[j]);
        }
    }
}

__global__ void convert_w(const float* __restrict__ w, __hip_bfloat16* __restrict__ wb) {
    int i = blockIdx.x * 256 + threadIdx.x;
    wb[i] = __float2bfloat16(w[i]);
}

__global__ __launch_bounds__(256, 2) void gemm_bf16(
        const __hip_bfloat16* __restrict__ A,
        const __hip_bfloat16* __restrict__ Bw,
        const float* __restrict__ bias,
        float* __restrict__ out) {
    __shared__ short Alds[TM * BK];
    __shared__ short Blds[TN * BK];
    int tile = blockIdx.x;
    int tm = tile >> 2, tn = tile & 3;
    int tid = threadIdx.x;
    int w = tid >> 6;
    int lane = tid & 63;
    int lo = lane & 15, quad = lane >> 4;
    int wm = w & 1, wn = w >> 1;
    int srow = lane >> 3;
    int cgp = lane & 7;

    floatx4 acc[4][4] = {};
    const short* Ag = (const short*)A;
    const short* Bg = (const short*)Bw;

    for (int k0 = 0; k0 < D; k0 += BK) {
        __syncthreads();
        #pragma unroll
        for (int t = 0; t < 4; t++) {
            int r = w * 32 + t * 8 + srow;
            int gg = cgp ^ srow;
            const short* ga = Ag + (size_t)(tm * TM + r) * D + k0 + gg * 8;
            const short* gb = Bg + (size_t)(tn * TN + r) * D + k0 + gg * 8;
            __builtin_amdgcn_global_load_lds(
                (const __attribute__((address_space(1))) void*)ga,
                (__attribute__((address_space(3))) void*)&Alds[(w * 32 + t * 8) * BK],
                16, 0, 0);
            __builtin_amdgcn_global_load_lds(
                (const __attribute__((address_space(1))) void*)gb,
                (__attribute__((address_space(3))) void*)&Blds[(w * 32 + t * 8) * BK],
                16, 0, 0);
        }
        __syncthreads();
        #pragma unroll
        for (int kk = 0; kk < 2; kk++) {
            short8 af[4], bfr[4];
            #pragma unroll
            for (int i = 0; i < 4; i++) {
                int ra = wm * 64 + i * 16 + lo;
                af[i] = *(const short8*)&Alds[ra * BK + (((kk << 2) | quad) ^ (lo & 7)) * 8];
                int rb = wn * 64 + i * 16 + lo;
                bfr[i] = *(const short8*)&Blds[rb * BK + (((kk << 2) | quad) ^ (lo & 7)) * 8];
            }
            #pragma unroll
            for (int i = 0; i < 4; i++)
                #pragma unroll
                for (int j = 0; j < 4; j++)
                    acc[i][j] = __builtin_amdgcn_mfma_f32_16x16x32_bf16(af[i], bfr[j], acc[i][j], 0, 0, 0);
        }
    }

    #pragma unroll
    for (int i = 0; i < 4; i++) {
        #pragma unroll
        for (int j = 0; j < 4; j++) {
            int n = tn * TN + wn * 64 + j * 16 + lo;
            float bv = bias[n];
            #pragma unroll
            for (int r = 0; r < 4; r++) {
                int m = tm * TM + wm * 64 + i * 16 + quad * 4 + r;
                out[(size_t)m * D + n] = acc[i][j][r] + bv;
            }
        }
    }
}

// ---------------------------------------------------------------------------

extern "C" void kernel_launch(void* const* d_in, const int* in_sizes, int n_in,
                              void* d_out, int out_size, void* d_ws, size_t ws_size,
                              hipStream_t stream) {
    const float* q   = (const float*)d_in[0];
    const float* k   = (const float*)d_in[1];
    const float* v   = (const float*)d_in[2];
    // d_in[3] = mask (unused)
    const float* W   = (const float*)d_in[4];
    const float* bfc = (const float*)d_in[5];
    float* out = (float*)d_out;

    char* ws = (char*)d_ws;
    __hip_bfloat16* attn = (__hip_bfloat16*)ws;                                   // 16 MiB
    __hip_bfloat16* wb   = (__hip_bfloat16*)(ws + (size_t)16 * 1024 * 1024);      // 512 KiB
    float* ksumT = (float*)(ws + (size_t)16 * 1024 * 1024 + 512 * 1024);          // 1 MiB
    float* vsumT = ksumT + BH * NCH * E;                                          // 1 MiB

    void* args[] = { (void*)&q, (void*)&k, (void*)&v, (void*)&W, (void*)&bfc,
                     (void*)&wb, (void*)&ksumT, (void*)&vsumT, (void*)&attn, (void*)&out };
    hipError_t err = hipLaunchCooperativeKernel((const void*)fused_linattn,
                                                dim3(512), dim3(256), args, 0, stream);
    if (err != hipSuccess) {
        (void)hipGetLastError();   // clear the error state
        hipLaunchKernelGGL(convert_w, dim3((D * D) / 256), dim3(256), 0, stream, W, wb);
        hipLaunchKernelGGL(chunk_sums, dim3(BH * NCH / 4), dim3(256), 0, stream, k, v, ksumT, vsumT);
        hipLaunchKernelGGL(chunk_prefix, dim3(BH * E / 4), dim3(256), 0, stream, ksumT, vsumT);
        hipLaunchKernelGGL(scan_attn, dim3(BH * NCH / 4), dim3(256), 0, stream, q, k, v, ksumT, vsumT, attn);
        hipLaunchKernelGGL(gemm_bf16, dim3((B * N / TM) * (D / TN)), dim3(256), 0, stream, attn, wb, bfc, out);
    }
}

// Round 6
// 225.972 us; speedup vs baseline: 1.5261x; 1.5261x over previous
//
#include <hip/hip_runtime.h>
#include <hip/hip_bf16.h>

// Problem dims (fixed by setup_inputs)
constexpr int B = 4, H = 8, N = 4096, E = 64, D = 512;   // d_model = H*E = 512
constexpr int BH = B * H;          // 32
constexpr int CHUNK = 32;          // positions per chunk
constexpr int NCH = N / CHUNK;     // 128 chunks per (b,h)
constexpr float EPS = 1e-5f;
constexpr int TM = 128, TN = 128;  // GEMM tile; K-slice = one head (64 dims)

typedef __attribute__((ext_vector_type(4))) float floatx4;
typedef __attribute__((ext_vector_type(8))) short short8;

__device__ __forceinline__ float phi(float x) {
    return (x > 0.0f) ? (x + 1.0f) : __expf(x);   // elu(x) + 1
}

// ---------------------------------------------------------------------------
// Kernel 1: per-(bh,chunk) sums of phi(k), v (transposed out: ksumT[bh*64+e][ch])
// + W -> bf16 folded in (grid is exactly 512*512 threads).
// grid: 1024 blocks x 256 threads, one wave per 32-chunk.
// ---------------------------------------------------------------------------
__global__ void chunk_sums(const float* __restrict__ k, const float* __restrict__ v,
                           const float* __restrict__ W, __hip_bfloat16* __restrict__ wb,
                           float* __restrict__ ksumT, float* __restrict__ vsumT) {
    int gid = blockIdx.x * 256 + threadIdx.x;
    wb[gid] = __float2bfloat16(W[gid]);

    int wave = (blockIdx.x << 2) | (threadIdx.x >> 6);   // chunk id 0..4095
    int lane = threadIdx.x & 63;
    int bh = wave >> 7, ch = wave & 127;
    int qd = lane >> 4;          // row-phase 0..3
    int c  = lane & 15;          // col-group (4 dims)
    const float* kp = k + ((size_t)bh * N + (size_t)ch * CHUNK) * E;
    const float* vp = v + ((size_t)bh * N + (size_t)ch * CHUNK) * E;
    floatx4 ks = {0.f, 0.f, 0.f, 0.f}, vs = {0.f, 0.f, 0.f, 0.f};
    #pragma unroll
    for (int i = 0; i < CHUNK / 4; i++) {
        int off = (i * 4 + qd) * E + c * 4;
        floatx4 kv = *(const floatx4*)(kp + off);
        floatx4 vv = *(const floatx4*)(vp + off);
        #pragma unroll
        for (int j = 0; j < 4; j++) ks[j] += phi(kv[j]);
        vs += vv;
    }
    #pragma unroll
    for (int j = 0; j < 4; j++) {
        ks[j] += __shfl_xor(ks[j], 16, 64);
        ks[j] += __shfl_xor(ks[j], 32, 64);
        vs[j] += __shfl_xor(vs[j], 16, 64);
        vs[j] += __shfl_xor(vs[j], 32, 64);
    }
    int d = c * 4 + qd;
    ksumT[(size_t)(bh * E + d) * NCH + ch] = ks[qd];
    vsumT[(size_t)(bh * E + d) * NCH + ch] = vs[qd];
}

// ---------------------------------------------------------------------------
// Kernel 2: exclusive prefix over 128 chunks per (bh,e). 2048 waves.
// ---------------------------------------------------------------------------
__global__ void chunk_prefix(float* __restrict__ ksumT, float* __restrict__ vsumT) {
    int wid = (blockIdx.x << 2) | (threadIdx.x >> 6);   // bh*64+e, 0..2047
    int lane = threadIdx.x & 63;
    size_t base = (size_t)wid * NCH;
    float x0 = ksumT[base + lane],      y0 = vsumT[base + lane];
    float x1 = ksumT[base + 64 + lane], y1 = vsumT[base + 64 + lane];
    float ox0 = x0, oy0 = y0, ox1 = x1, oy1 = y1;
    #pragma unroll
    for (int dlt = 1; dlt < 64; dlt <<= 1) {
        float t0 = __shfl_up(x0, dlt, 64);
        float u0 = __shfl_up(y0, dlt, 64);
        float t1 = __shfl_up(x1, dlt, 64);
        float u1 = __shfl_up(y1, dlt, 64);
        if (lane >= dlt) { x0 += t0; y0 += u0; x1 += t1; y1 += u1; }
    }
    float tx = __shfl(x0, 63, 64);
    float ty = __shfl(y0, 63, 64);
    ksumT[base + lane]      = x0 - ox0;
    vsumT[base + lane]      = y0 - oy0;
    ksumT[base + 64 + lane] = x1 - ox1 + tx;
    vsumT[base + 64 + lane] = y1 - oy1 + ty;
}

// ---------------------------------------------------------------------------
// Kernel 3: fused scan + GEMM. out[m=b*N+n][dm] = attn[m] @ wb^T + bias.
// 512 blocks x 256 thr (2 blocks/CU). Tile 128x128, K-loop over 8 heads
// (K-slice 64 = head h's dims). Per head:
//   - stage W rows (tn*128.., cols h*64..) via global_load_lds (XOR swizzle)
//   - each wave recomputes attn for its 32 rows (= exactly one chunk) from
//     q,k,v + chunk offsets; writes bf16 into LDS with the SAME swizzle
//   - 2x16 MFMA 16x16x32_bf16
// attn never touches HBM. Same-tm blocks are 128 apart -> same XCD.
// ---------------------------------------------------------------------------
__global__ __launch_bounds__(256, 2) void scan_gemm(
        const float* __restrict__ q, const float* __restrict__ k,
        const float* __restrict__ v,
        const __hip_bfloat16* __restrict__ wb,
        const float* __restrict__ ksumT, const float* __restrict__ vsumT,
        const float* __restrict__ bias, float* __restrict__ out) {
    __shared__ short Alds[TM * 64];   // 16 KiB attn tile (bf16, swizzled colgrps)
    __shared__ short Blds[TN * 64];   // 16 KiB W tile
    const int tile = blockIdx.x;
    const int tm = tile & 127, tn = tile >> 7;
    const int tid = threadIdx.x;
    const int w = tid >> 6;           // wave 0..3; wave w's rows = chunk tm*4+... see ch
    const int lane = tid & 63;        // = dim e in the scan part
    const int lo = lane & 15, quad = lane >> 4;
    const int wm = w & 1, wn = w >> 1;
    const int srow = lane >> 3;       // 0..7
    const int cgp = lane & 7;         // colgrp slot
    const int b_ = tm >> 5;           // batch
    const int n0 = (tm & 31) * 128;   // first position of this M-tile
    const int ch = (tm & 31) * 4 + w; // this wave's chunk within (b,h)

    floatx4 acc[4][4] = {};

    for (int h = 0; h < 8; h++) {
        const int k0 = h * 64;
        const int bh = b_ * 8 + h;
        __syncthreads();              // previous iter's LDS reads done
        // ---- stage W tile (B operand), proven R3 pattern ----
        #pragma unroll
        for (int t = 0; t < 4; t++) {
            int r = w * 32 + t * 8 + srow;
            int gg = cgp ^ srow;
            const short* gb = (const short*)wb + (size_t)(tn * TN + r) * D + k0 + gg * 8;
            __builtin_amdgcn_global_load_lds(
                (const __attribute__((address_space(1))) void*)gb,
                (__attribute__((address_space(3))) void*)&Blds[(w * 32 + t * 8) * 64],
                16, 0, 0);
        }
        // ---- recompute attn for rows w*32..w*32+31 of head h ----
        {
            size_t gbase = ((size_t)bh * N + n0 + w * 32) * E + lane;
            const float* qp = q + gbase;
            const float* kp = k + gbase;
            const float* vp = v + gbase;
            float koff = ksumT[(size_t)(bh * E + lane) * NCH + ch];
            float voff = vsumT[(size_t)(bh * E + lane) * NCH + ch];
            float kc = 0.f, vc = 0.f;
            #pragma unroll
            for (int g = 0; g < 4; g++) {
                float kb[8], qb[8], vb[8], pr[8], sv[8];
                #pragma unroll
                for (int j = 0; j < 8; j++) {
                    size_t o = (size_t)(g * 8 + j) * E;
                    kb[j] = kp[o]; qb[j] = qp[o]; vb[j] = vp[o];
                }
                #pragma unroll
                for (int j = 0; j < 8; j++) {
                    kc += phi(kb[j]);
                    vc += vb[j];
                    pr[j] = phi(qb[j]) * (koff + kc);
                    sv[j] = voff + vc;
                }
                #pragma unroll
                for (int m = 1; m < 64; m <<= 1) {
                    #pragma unroll
                    for (int j = 0; j < 8; j++) pr[j] += __shfl_xor(pr[j], m, 64);
                }
                #pragma unroll
                for (int j = 0; j < 8; j++) {
                    float s = pr[j];
                    __hip_bfloat16 val = __float2bfloat16(s / (s + EPS) * sv[j]);
                    int p = w * 32 + g * 8 + j;
                    // store dim e of row p at swizzled colgrp (e>>3)^(p&7)
                    Alds[p * 64 + ((((lane >> 3) ^ (p & 7)) << 3) | (lane & 7))] =
                        *reinterpret_cast<short*>(&val);
                }
            }
        }
        __syncthreads();              // A writes visible + B staging drained
        // ---- MFMA over this 64-deep K slice ----
        #pragma unroll
        for (int kk = 0; kk < 2; kk++) {
            short8 af[4], bfr[4];
            #pragma unroll
            for (int i = 0; i < 4; i++) {
                int ra = wm * 64 + i * 16 + lo;
                af[i] = *(const short8*)&Alds[ra * 64 + (((kk << 2) | quad) ^ (lo & 7)) * 8];
                int rb = wn * 64 + i * 16 + lo;
                bfr[i] = *(const short8*)&Blds[rb * 64 + (((kk << 2) | quad) ^ (lo & 7)) * 8];
            }
            #pragma unroll
            for (int i = 0; i < 4; i++)
                #pragma unroll
                for (int j = 0; j < 4; j++)
                    acc[i][j] = __builtin_amdgcn_mfma_f32_16x16x32_bf16(af[i], bfr[j], acc[i][j], 0, 0, 0);
        }
    }

    // ---- epilogue ----
    #pragma unroll
    for (int i = 0; i < 4; i++) {
        #pragma unroll
        for (int j = 0; j < 4; j++) {
            int n = tn * TN + wn * 64 + j * 16 + lo;
            float bv = bias[n];
            #pragma unroll
            for (int r = 0; r < 4; r++) {
                int m = tm * TM + wm * 64 + i * 16 + quad * 4 + r;
                out[(size_t)m * D + n] = acc[i][j][r] + bv;
            }
        }
    }
}

// ---------------------------------------------------------------------------

extern "C" void kernel_launch(void* const* d_in, const int* in_sizes, int n_in,
                              void* d_out, int out_size, void* d_ws, size_t ws_size,
                              hipStream_t stream) {
    const float* q   = (const float*)d_in[0];
    const float* k   = (const float*)d_in[1];
    const float* v   = (const float*)d_in[2];
    // d_in[3] = mask (unused)
    const float* W   = (const float*)d_in[4];
    const float* bfc = (const float*)d_in[5];
    float* out = (float*)d_out;

    char* ws = (char*)d_ws;
    __hip_bfloat16* wb = (__hip_bfloat16*)ws;                 // 512 KiB
    float* ksumT = (float*)(ws + 512 * 1024);                 // 1 MiB
    float* vsumT = ksumT + BH * NCH * E;                      // 1 MiB

    hipLaunchKernelGGL(chunk_sums, dim3(BH * NCH / 4), dim3(256), 0, stream,
                       k, v, W, wb, ksumT, vsumT);
    hipLaunchKernelGGL(chunk_prefix, dim3(BH * E / 4), dim3(256), 0, stream, ksumT, vsumT);
    hipLaunchKernelGGL(scan_gemm, dim3((B * N / TM) * (D / TN)), dim3(256), 0, stream,
                       q, k, v, wb, ksumT, vsumT, bfc, out);
}